// Round 1
// baseline (2859.447 us; speedup 1.0000x reference)
//
#include <hip/hip_runtime.h>

// Problem constants
#define DI 1536
#define DM 768
#define NS 16
#define RK 48
#define LQ 512
#define BB 2
#define MROWS (BB*LQ)   // 1024

typedef short bf16x8 __attribute__((ext_vector_type(8)));
typedef float f32x4 __attribute__((ext_vector_type(4)));

static __device__ __forceinline__ short f2bf(float f) {
  unsigned u = __float_as_uint(f);
  u += 0x7FFF + ((u >> 16) & 1);   // round-to-nearest-even
  return (short)(u >> 16);
}

// ---------------- embedding gather ----------------
__global__ __launch_bounds__(256) void k_gather(const int* __restrict__ ids,
                                                const int* __restrict__ mask,
                                                const float* __restrict__ embed,
                                                float* __restrict__ h) {
  int row = blockIdx.x;                 // 0..1023 = b*512 + l
  int id = ids[row];
  float mk = (float)mask[row];
  const float* src = embed + (size_t)id * DM;
  float* dst = h + (size_t)row * DM;
  for (int i = threadIdx.x; i < DM; i += 256) dst[i] = src[i] * mk;
}

// ---------------- rmsnorm (768 per row) ----------------
__global__ __launch_bounds__(256) void k_rmsnorm(const float* __restrict__ h,
                                                 const float* __restrict__ w,
                                                 float* __restrict__ out) {
  int row = blockIdx.x;
  const float* x = h + (size_t)row * DM;
  int tid = threadIdx.x;
  float v0 = x[tid], v1 = x[tid + 256], v2 = x[tid + 512];
  float ss = v0*v0 + v1*v1 + v2*v2;
  #pragma unroll
  for (int o = 32; o > 0; o >>= 1) ss += __shfl_xor(ss, o);
  __shared__ float ps[4];
  if ((tid & 63) == 0) ps[tid >> 6] = ss;
  __syncthreads();
  float tot = ps[0] + ps[1] + ps[2] + ps[3];
  float scale = rsqrtf(tot * (1.0f/768.0f) + 1e-5f);
  float* o0 = out + (size_t)row * DM;
  o0[tid]       = v0 * scale * w[tid];
  o0[tid + 256] = v1 * scale * w[tid + 256];
  o0[tid + 512] = v2 * scale * w[tid + 512];
}

// ---------------- bf16 MFMA GEMM: C[m,n] = sum_k A[m,k]*B[n,k] (+C) ----------------
// A: M x K row-major (M multiple of TM*32), B: N x K row-major (N tail OK), C: M x N
template<int TM, int TN, bool RES>
__global__ __launch_bounds__(256) void k_gemm_nt(const float* __restrict__ A,
                                                 const float* __restrict__ B,
                                                 float* __restrict__ C,
                                                 int M, int N, int K) {
  constexpr int BM = TM*32, BN = TN*32, BK = 32, SK = 40;  // SK pad: 80B rows, 2-way-only LDS conflicts
  __shared__ short As[BM*SK];
  __shared__ short Bs[BN*SK];
  const int m0 = blockIdx.y * BM, n0 = blockIdx.x * BN;
  const int tid = threadIdx.x;
  const int wave = tid >> 6, lane = tid & 63;
  const int wm = (wave >> 1) * (TM*16), wn = (wave & 1) * (TN*16);
  const int lm = lane & 15, q = lane >> 4;
  const int trow = tid >> 3;          // 0..31
  const int tcol = (tid & 7) * 4;     // 0..28
  f32x4 acc[TM][TN] = {};
  for (int kt = 0; kt < K; kt += BK) {
    float4 av[TM], bv[TN];
    #pragma unroll
    for (int p = 0; p < TM; p++)
      av[p] = *(const float4*)(A + (size_t)(m0 + p*32 + trow)*K + kt + tcol);
    #pragma unroll
    for (int p = 0; p < TN; p++) {
      int bn = n0 + p*32 + trow;
      bv[p] = (bn < N) ? *(const float4*)(B + (size_t)bn*K + kt + tcol)
                       : make_float4(0.f, 0.f, 0.f, 0.f);
    }
    __syncthreads();   // previous iteration's LDS reads done
    #pragma unroll
    for (int p = 0; p < TM; p++) {
      short4 s; s.x = f2bf(av[p].x); s.y = f2bf(av[p].y); s.z = f2bf(av[p].z); s.w = f2bf(av[p].w);
      *(short4*)(&As[(p*32 + trow)*SK + tcol]) = s;
    }
    #pragma unroll
    for (int p = 0; p < TN; p++) {
      short4 s; s.x = f2bf(bv[p].x); s.y = f2bf(bv[p].y); s.z = f2bf(bv[p].z); s.w = f2bf(bv[p].w);
      *(short4*)(&Bs[(p*32 + trow)*SK + tcol]) = s;
    }
    __syncthreads();
    bf16x8 af[TM], bfr[TN];
    #pragma unroll
    for (int i = 0; i < TM; i++)
      af[i] = *(const bf16x8*)(&As[(wm + i*16 + lm)*SK + q*8]);
    #pragma unroll
    for (int j = 0; j < TN; j++)
      bfr[j] = *(const bf16x8*)(&Bs[(wn + j*16 + lm)*SK + q*8]);
    #pragma unroll
    for (int i = 0; i < TM; i++)
      #pragma unroll
      for (int j = 0; j < TN; j++)
        acc[i][j] = __builtin_amdgcn_mfma_f32_16x16x32_bf16(af[i], bfr[j], acc[i][j], 0, 0, 0);
  }
  // epilogue: C/D layout col = lane&15, row = (lane>>4)*4 + reg
  #pragma unroll
  for (int i = 0; i < TM; i++) {
    #pragma unroll
    for (int j = 0; j < TN; j++) {
      int rm = m0 + wm + i*16 + q*4;
      int cn = n0 + wn + j*16 + lm;
      if (cn < N) {
        float* cp = C + (size_t)rm*N + cn;
        #pragma unroll
        for (int r2 = 0; r2 < 4; r2++) {
          float v = acc[i][j][r2];
          if (RES) v += cp[(size_t)r2*N];
          cp[(size_t)r2*N] = v;
        }
      }
    }
  }
}

// ---------------- causal depthwise conv (K=4) + bias + silu ----------------
__global__ __launch_bounds__(256) void k_conv(const float* __restrict__ xz,
                                              const float* __restrict__ cw,
                                              const float* __restrict__ cb,
                                              float* __restrict__ xs) {
  int idx = blockIdx.x * 256 + threadIdx.x;      // over 2*512*1536
  int d = idx % DI;
  int t = (idx / DI) % LQ;
  int b = idx / (DI * LQ);
  const float* xcol = xz + (size_t)b * LQ * (2*DI) + d;   // x[b,:,d], stride 3072
  float acc = cb[d];
  #pragma unroll
  for (int k = 0; k < 4; k++) {
    int tt = t + k - 3;
    if (tt >= 0) acc += cw[d*4 + k] * xcol[(size_t)tt * (2*DI)];
  }
  float s = acc / (1.0f + expf(-acc));   // silu
  xs[idx] = s;
}

// ---------------- x_proj: proj[m, 0:80] = xs[m,:] . w[n,:] ----------------
__global__ __launch_bounds__(256) void k_proj(const float* __restrict__ xs,
                                              const float* __restrict__ w,
                                              float* __restrict__ proj) {
  int wave = threadIdx.x >> 6, lane = threadIdx.x & 63;
  int m = blockIdx.x * 4 + wave;                 // one row per wave
  const float* xr = xs + (size_t)m * DI;
  float xv[24];
  #pragma unroll
  for (int j = 0; j < 24; j++) xv[j] = xr[lane + j*64];
  for (int n = 0; n < 80; n++) {
    const float* wr = w + (size_t)n * DI;
    float acc = 0.f;
    #pragma unroll
    for (int j = 0; j < 24; j++) acc += xv[j] * wr[lane + j*64];
    #pragma unroll
    for (int o = 32; o > 0; o >>= 1) acc += __shfl_xor(acc, o);
    if (lane == 0) proj[(size_t)m * 80 + n] = acc;
  }
}

// ---------------- dt = softplus(dt_r @ dtw^T + dtb) ----------------
__global__ __launch_bounds__(256) void k_dt(const float* __restrict__ proj,
                                            const float* __restrict__ dtw,
                                            const float* __restrict__ dtb,
                                            float* __restrict__ dt) {
  int m = blockIdx.y;
  int d = blockIdx.x * 256 + threadIdx.x;
  __shared__ float p[RK];
  if (threadIdx.x < RK) p[threadIdx.x] = proj[(size_t)m * 80 + threadIdx.x];
  __syncthreads();
  const float* wr = dtw + (size_t)d * RK;
  float acc = dtb[d];
  #pragma unroll
  for (int r = 0; r < RK; r++) acc += p[r] * wr[r];
  float sp = (acc > 20.f) ? acc : log1pf(expf(acc));
  dt[(size_t)m * DI + d] = sp;
}

// ---------------- selective scan + Dp*x + silu(z) gating ----------------
// lane = (seq & 3-within-wave)*16 + n ; wave handles 4 (b,d) sequences
__global__ __launch_bounds__(256) void k_scan(const float* __restrict__ dt,
                                              const float* __restrict__ proj,
                                              const float* __restrict__ xs,
                                              const float* __restrict__ xz,
                                              const float* __restrict__ A_log,
                                              const float* __restrict__ Dp,
                                              float* __restrict__ y) {
  int gtid = blockIdx.x * 256 + threadIdx.x;     // 192*256 = 49152 = 3072 seq * 16
  int n = gtid & 15;
  int seq = gtid >> 4;                            // b*1536 + d
  int b = seq / DI, d = seq % DI;
  float negA = -expf(A_log[d * NS + n]);
  float Dv = Dp[d];
  const float* dtp = dt   + (size_t)b * LQ * DI + d;
  const float* xp  = xs   + (size_t)b * LQ * DI + d;
  const float* zp  = xz   + (size_t)b * LQ * (2*DI) + DI + d;
  const float* Bp  = proj + (size_t)b * LQ * 80 + RK + n;
  const float* Cp  = proj + (size_t)b * LQ * 80 + RK + NS + n;
  float* yp = y + (size_t)b * LQ * DI + d;
  float h = 0.f;
  #pragma unroll 2
  for (int t = 0; t < LQ; t++) {
    float dtv = dtp[(size_t)t * DI];
    float xv  = xp[(size_t)t * DI];
    float Bv  = Bp[(size_t)t * 80];
    float Cv  = Cp[(size_t)t * 80];
    float a = expf(dtv * negA);
    h = a * h + dtv * Bv * xv;
    float yy = h * Cv;
    yy += __shfl_xor(yy, 1);
    yy += __shfl_xor(yy, 2);
    yy += __shfl_xor(yy, 4);
    yy += __shfl_xor(yy, 8);
    if (n == 0) {
      float zv = zp[(size_t)t * (2*DI)];
      float sz = zv / (1.0f + expf(-zv));
      yp[(size_t)t * DI] = (yy + Dv * xv) * sz;
    }
  }
}

extern "C" void kernel_launch(void* const* d_in, const int* in_sizes, int n_in,
                              void* d_out, int out_size, void* d_ws, size_t ws_size,
                              hipStream_t stream) {
  const int*   q_ids        = (const int*)d_in[0];
  const int*   q_mask       = (const int*)d_in[1];
  const float* embed        = (const float*)d_in[4];
  const float* in_proj_w    = (const float*)d_in[5];
  const float* conv_w       = (const float*)d_in[6];
  const float* conv_b       = (const float*)d_in[7];
  const float* x_proj_w     = (const float*)d_in[8];
  const float* dt_proj_w    = (const float*)d_in[9];
  const float* dt_proj_b    = (const float*)d_in[10];
  const float* A_log        = (const float*)d_in[11];
  const float* Dp           = (const float*)d_in[12];
  const float* out_proj_w   = (const float*)d_in[13];
  const float* norm_w       = (const float*)d_in[14];
  const float* final_norm_w = (const float*)d_in[15];
  float* out = (float*)d_out;

  // workspace layout (floats)
  float* ws = (float*)d_ws;
  float* h   = ws;                    // 1024*768
  float* r   = h  + 786432;           // 1024*768
  float* xz  = r  + 786432;           // 1024*3072
  float* xs  = xz + 3145728;          // 1024*1536
  float* pj  = xs + 1572864;          // 1024*80
  float* dtb = pj + 81920;            // 1024*1536
  float* y   = dtb + 1572864;         // 1024*1536

  k_gather<<<MROWS, 256, 0, stream>>>(q_ids, q_mask, embed, h);

  for (int l = 0; l < 4; l++) {
    k_rmsnorm<<<MROWS, 256, 0, stream>>>(h, norm_w + (size_t)l*DM, r);
    // xz = r @ in_proj_w[l]^T : M=1024 N=3072 K=768 (64x128 tiles)
    k_gemm_nt<2,4,false><<<dim3(3072/128, MROWS/64), 256, 0, stream>>>(
        r, in_proj_w + (size_t)l*2*DI*DM, xz, MROWS, 2*DI, DM);
    k_conv<<<(MROWS*DI)/256, 256, 0, stream>>>(xz, conv_w + (size_t)l*DI*4,
                                               conv_b + (size_t)l*DI, xs);
    k_proj<<<MROWS/4, 256, 0, stream>>>(xs, x_proj_w + (size_t)l*80*DI, pj);
    k_dt<<<dim3(DI/256, MROWS), 256, 0, stream>>>(pj, dt_proj_w + (size_t)l*DI*RK,
                                                  dt_proj_b + (size_t)l*DI, dtb);
    k_scan<<<(MROWS/4*DI/256)/16*16 ? 192 : 192, 256, 0, stream>>>(
        dtb, pj, xs, xz, A_log + (size_t)l*DI*NS, Dp + (size_t)l*DI, y);
    // h += y @ out_proj_w[l]^T : M=1024 N=768 K=1536 (64x64 tiles)
    k_gemm_nt<2,2,true><<<dim3(DM/64, MROWS/64), 256, 0, stream>>>(
        y, out_proj_w + (size_t)l*DM*DI, h, MROWS, DM, DI);
  }

  k_rmsnorm<<<MROWS, 256, 0, stream>>>(h, final_norm_w, r);
  // logits = r @ embed^T : M=1024 N=50280 K=768 (128x128 tiles)
  k_gemm_nt<4,4,false><<<dim3((50280 + 127)/128, MROWS/128), 256, 0, stream>>>(
      r, embed, out, MROWS, 50280, 768);
}

// Round 2
// 1671.992 us; speedup vs baseline: 1.7102x; 1.7102x over previous
//
#include <hip/hip_runtime.h>

// Problem constants
#define DI 1536
#define DM 768
#define NS 16
#define RK 48
#define LQ 512
#define BB 2
#define MROWS (BB*LQ)   // 1024

typedef short bf16x8 __attribute__((ext_vector_type(8)));
typedef float f32x4 __attribute__((ext_vector_type(4)));

static __device__ __forceinline__ short f2bf(float f) {
  unsigned u = __float_as_uint(f);
  u += 0x7FFF + ((u >> 16) & 1);   // round-to-nearest-even
  return (short)(u >> 16);
}

// ---------------- embedding gather ----------------
__global__ __launch_bounds__(256) void k_gather(const int* __restrict__ ids,
                                                const int* __restrict__ mask,
                                                const float* __restrict__ embed,
                                                float* __restrict__ h) {
  int row = blockIdx.x;                 // 0..1023 = b*512 + l
  int id = ids[row];
  float mk = (float)mask[row];
  const float* src = embed + (size_t)id * DM;
  float* dst = h + (size_t)row * DM;
  for (int i = threadIdx.x; i < DM; i += 256) dst[i] = src[i] * mk;
}

// ---------------- rmsnorm (768 per row) ----------------
__global__ __launch_bounds__(256) void k_rmsnorm(const float* __restrict__ h,
                                                 const float* __restrict__ w,
                                                 float* __restrict__ out) {
  int row = blockIdx.x;
  const float* x = h + (size_t)row * DM;
  int tid = threadIdx.x;
  float v0 = x[tid], v1 = x[tid + 256], v2 = x[tid + 512];
  float ss = v0*v0 + v1*v1 + v2*v2;
  #pragma unroll
  for (int o = 32; o > 0; o >>= 1) ss += __shfl_xor(ss, o);
  __shared__ float ps[4];
  if ((tid & 63) == 0) ps[tid >> 6] = ss;
  __syncthreads();
  float tot = ps[0] + ps[1] + ps[2] + ps[3];
  float scale = rsqrtf(tot * (1.0f/768.0f) + 1e-5f);
  float* o0 = out + (size_t)row * DM;
  o0[tid]       = v0 * scale * w[tid];
  o0[tid + 256] = v1 * scale * w[tid + 256];
  o0[tid + 512] = v2 * scale * w[tid + 512];
}

// ---------------- bf16 MFMA GEMM: C[m,n] = sum_k A[m,k]*B[n,k] (+C) ----------------
// A: M x K row-major (M multiple of TM*32), B: N x K row-major (N tail OK), C: M x N
template<int TM, int TN, bool RES>
__global__ __launch_bounds__(256) void k_gemm_nt(const float* __restrict__ A,
                                                 const float* __restrict__ B,
                                                 float* __restrict__ C,
                                                 int M, int N, int K) {
  constexpr int BM = TM*32, BN = TN*32, BK = 32, SK = 40;  // SK pad: 80B rows, 2-way-only LDS conflicts
  __shared__ short As[BM*SK];
  __shared__ short Bs[BN*SK];
  const int m0 = blockIdx.y * BM, n0 = blockIdx.x * BN;
  const int tid = threadIdx.x;
  const int wave = tid >> 6, lane = tid & 63;
  const int wm = (wave >> 1) * (TM*16), wn = (wave & 1) * (TN*16);
  const int lm = lane & 15, q = lane >> 4;
  const int trow = tid >> 3;          // 0..31
  const int tcol = (tid & 7) * 4;     // 0..28
  f32x4 acc[TM][TN] = {};
  for (int kt = 0; kt < K; kt += BK) {
    float4 av[TM], bv[TN];
    #pragma unroll
    for (int p = 0; p < TM; p++)
      av[p] = *(const float4*)(A + (size_t)(m0 + p*32 + trow)*K + kt + tcol);
    #pragma unroll
    for (int p = 0; p < TN; p++) {
      int bn = n0 + p*32 + trow;
      bv[p] = (bn < N) ? *(const float4*)(B + (size_t)bn*K + kt + tcol)
                       : make_float4(0.f, 0.f, 0.f, 0.f);
    }
    __syncthreads();   // previous iteration's LDS reads done
    #pragma unroll
    for (int p = 0; p < TM; p++) {
      short4 s; s.x = f2bf(av[p].x); s.y = f2bf(av[p].y); s.z = f2bf(av[p].z); s.w = f2bf(av[p].w);
      *(short4*)(&As[(p*32 + trow)*SK + tcol]) = s;
    }
    #pragma unroll
    for (int p = 0; p < TN; p++) {
      short4 s; s.x = f2bf(bv[p].x); s.y = f2bf(bv[p].y); s.z = f2bf(bv[p].z); s.w = f2bf(bv[p].w);
      *(short4*)(&Bs[(p*32 + trow)*SK + tcol]) = s;
    }
    __syncthreads();
    bf16x8 af[TM], bfr[TN];
    #pragma unroll
    for (int i = 0; i < TM; i++)
      af[i] = *(const bf16x8*)(&As[(wm + i*16 + lm)*SK + q*8]);
    #pragma unroll
    for (int j = 0; j < TN; j++)
      bfr[j] = *(const bf16x8*)(&Bs[(wn + j*16 + lm)*SK + q*8]);
    #pragma unroll
    for (int i = 0; i < TM; i++)
      #pragma unroll
      for (int j = 0; j < TN; j++)
        acc[i][j] = __builtin_amdgcn_mfma_f32_16x16x32_bf16(af[i], bfr[j], acc[i][j], 0, 0, 0);
  }
  // epilogue: C/D layout col = lane&15, row = (lane>>4)*4 + reg
  #pragma unroll
  for (int i = 0; i < TM; i++) {
    #pragma unroll
    for (int j = 0; j < TN; j++) {
      int rm = m0 + wm + i*16 + q*4;
      int cn = n0 + wn + j*16 + lm;
      if (cn < N) {
        float* cp = C + (size_t)rm*N + cn;
        #pragma unroll
        for (int r2 = 0; r2 < 4; r2++) {
          float v = acc[i][j][r2];
          if (RES) v += cp[(size_t)r2*N];
          cp[(size_t)r2*N] = v;
        }
      }
    }
  }
}

// ---------------- causal depthwise conv (K=4) + bias + silu ----------------
__global__ __launch_bounds__(256) void k_conv(const float* __restrict__ xz,
                                              const float* __restrict__ cw,
                                              const float* __restrict__ cb,
                                              float* __restrict__ xs) {
  int idx = blockIdx.x * 256 + threadIdx.x;      // over 2*512*1536
  int d = idx % DI;
  int t = (idx / DI) % LQ;
  int b = idx / (DI * LQ);
  const float* xcol = xz + (size_t)b * LQ * (2*DI) + d;   // x[b,:,d], stride 3072
  float acc = cb[d];
  #pragma unroll
  for (int k = 0; k < 4; k++) {
    int tt = t + k - 3;
    if (tt >= 0) acc += cw[d*4 + k] * xcol[(size_t)tt * (2*DI)];
  }
  float s = acc / (1.0f + expf(-acc));   // silu
  xs[idx] = s;
}

// ---------------- x_proj: proj[m, 0:80] = xs[m,:] . w[n,:] ----------------
__global__ __launch_bounds__(256) void k_proj(const float* __restrict__ xs,
                                              const float* __restrict__ w,
                                              float* __restrict__ proj) {
  int wave = threadIdx.x >> 6, lane = threadIdx.x & 63;
  int m = blockIdx.x * 4 + wave;                 // one row per wave
  const float* xr = xs + (size_t)m * DI;
  float xv[24];
  #pragma unroll
  for (int j = 0; j < 24; j++) xv[j] = xr[lane + j*64];
  for (int n = 0; n < 80; n++) {
    const float* wr = w + (size_t)n * DI;
    float acc = 0.f;
    #pragma unroll
    for (int j = 0; j < 24; j++) acc += xv[j] * wr[lane + j*64];
    #pragma unroll
    for (int o = 32; o > 0; o >>= 1) acc += __shfl_xor(acc, o);
    if (lane == 0) proj[(size_t)m * 80 + n] = acc;
  }
}

// ---------------- dt = softplus(dt_r @ dtw^T + dtb) ----------------
__global__ __launch_bounds__(256) void k_dt(const float* __restrict__ proj,
                                            const float* __restrict__ dtw,
                                            const float* __restrict__ dtb,
                                            float* __restrict__ dt) {
  int m = blockIdx.y;
  int d = blockIdx.x * 256 + threadIdx.x;
  __shared__ float p[RK];
  if (threadIdx.x < RK) p[threadIdx.x] = proj[(size_t)m * 80 + threadIdx.x];
  __syncthreads();
  const float* wr = dtw + (size_t)d * RK;
  float acc = dtb[d];
  #pragma unroll
  for (int r = 0; r < RK; r++) acc += p[r] * wr[r];
  float sp = (acc > 20.f) ? acc : log1pf(expf(acc));
  dt[(size_t)m * DI + d] = sp;
}

// ---------------- chunked selective scan ----------------
// One block per (b,d). Thread (c,n): c = chunk (16 chunks of 32 steps), n = state.
// Pass 1: batched register preload + per-chunk carry (P = prod a, H = local state).
// Pass 2: 16-wide exclusive carry scan in LDS.
// Pass 3: register replay; writes yraw[t] = sum_n h_t[n]*C_t[n].
#define SCT 32   // chunk length
__global__ __launch_bounds__(256) void k_scan(const float* __restrict__ dt,
                                              const float* __restrict__ proj,
                                              const float* __restrict__ xs,
                                              const float* __restrict__ A_log,
                                              float* __restrict__ y) {
  const int d = blockIdx.x;        // 0..1535
  const int b = blockIdx.y;        // 0..1
  const int tid = threadIdx.x;
  const int n = tid & 15;
  const int c = tid >> 4;          // 0..15
  const int t0 = c * SCT;
  const float negA = -expf(A_log[d * NS + n]);
  const float* dtp = dt   + (size_t)b * LQ * DI + d;
  const float* xp  = xs   + (size_t)b * LQ * DI + d;
  const float* Bp  = proj + (size_t)b * LQ * 80 + RK + n;
  const float* Cp  = proj + (size_t)b * LQ * 80 + RK + NS + n;

  float a[SCT], u[SCT], Cv[SCT];
  #pragma unroll
  for (int j = 0; j < SCT; j++) {
    int t = t0 + j;
    float dtv = dtp[(size_t)t * DI];
    float xv  = xp[(size_t)t * DI];
    float Bv  = Bp[(size_t)t * 80];
    Cv[j]     = Cp[(size_t)t * 80];
    a[j] = expf(dtv * negA);
    u[j] = dtv * Bv * xv;
  }
  // per-chunk carry
  float P = 1.f, H = 0.f;
  #pragma unroll
  for (int j = 0; j < SCT; j++) { H = a[j]*H + u[j]; P *= a[j]; }

  __shared__ float Ps[16][16], Hs[16][16], Ss[16][16];
  Ps[c][n] = P; Hs[c][n] = H;
  __syncthreads();
  if (tid < 16) {          // lane nn scans its 16 chunk carries serially
    float S = 0.f;
    #pragma unroll
    for (int cc = 0; cc < 16; cc++) {
      Ss[cc][tid] = S;
      S = Ps[cc][tid] * S + Hs[cc][tid];
    }
  }
  __syncthreads();

  float h = Ss[c][n];
  float* yp = y + (size_t)b * LQ * DI + d;
  #pragma unroll
  for (int j = 0; j < SCT; j++) {
    h = a[j]*h + u[j];
    float yy = h * Cv[j];
    yy += __shfl_xor(yy, 1);
    yy += __shfl_xor(yy, 2);
    yy += __shfl_xor(yy, 4);
    yy += __shfl_xor(yy, 8);
    if (n == 0) yp[(size_t)(t0 + j) * DI] = yy;
  }
}

// ---------------- y = (yraw + Dp*x) * silu(z) ----------------
__global__ __launch_bounds__(256) void k_gate(float* __restrict__ y,
                                              const float* __restrict__ xs,
                                              const float* __restrict__ xz,
                                              const float* __restrict__ Dp) {
  int idx = blockIdx.x * 256 + threadIdx.x;   // over 2*512*1536
  int d = idx % DI;
  int bt = idx / DI;                          // b*512 + t
  float zv = xz[(size_t)bt * (2*DI) + DI + d];
  float sz = zv / (1.0f + expf(-zv));
  y[idx] = (y[idx] + Dp[d] * xs[idx]) * sz;
}

extern "C" void kernel_launch(void* const* d_in, const int* in_sizes, int n_in,
                              void* d_out, int out_size, void* d_ws, size_t ws_size,
                              hipStream_t stream) {
  const int*   q_ids        = (const int*)d_in[0];
  const int*   q_mask       = (const int*)d_in[1];
  const float* embed        = (const float*)d_in[4];
  const float* in_proj_w    = (const float*)d_in[5];
  const float* conv_w       = (const float*)d_in[6];
  const float* conv_b       = (const float*)d_in[7];
  const float* x_proj_w     = (const float*)d_in[8];
  const float* dt_proj_w    = (const float*)d_in[9];
  const float* dt_proj_b    = (const float*)d_in[10];
  const float* A_log        = (const float*)d_in[11];
  const float* Dp           = (const float*)d_in[12];
  const float* out_proj_w   = (const float*)d_in[13];
  const float* norm_w       = (const float*)d_in[14];
  const float* final_norm_w = (const float*)d_in[15];
  float* out = (float*)d_out;

  // workspace layout (floats)
  float* ws = (float*)d_ws;
  float* h   = ws;                    // 1024*768
  float* r   = h  + 786432;           // 1024*768
  float* xz  = r  + 786432;           // 1024*3072
  float* xs  = xz + 3145728;          // 1024*1536
  float* pj  = xs + 1572864;          // 1024*80
  float* dtb = pj + 81920;            // 1024*1536
  float* y   = dtb + 1572864;         // 1024*1536

  k_gather<<<MROWS, 256, 0, stream>>>(q_ids, q_mask, embed, h);

  for (int l = 0; l < 4; l++) {
    k_rmsnorm<<<MROWS, 256, 0, stream>>>(h, norm_w + (size_t)l*DM, r);
    // xz = r @ in_proj_w[l]^T : M=1024 N=3072 K=768 (64x128 tiles)
    k_gemm_nt<2,4,false><<<dim3(3072/128, MROWS/64), 256, 0, stream>>>(
        r, in_proj_w + (size_t)l*2*DI*DM, xz, MROWS, 2*DI, DM);
    k_conv<<<(MROWS*DI)/256, 256, 0, stream>>>(xz, conv_w + (size_t)l*DI*4,
                                               conv_b + (size_t)l*DI, xs);
    k_proj<<<MROWS/4, 256, 0, stream>>>(xs, x_proj_w + (size_t)l*80*DI, pj);
    k_dt<<<dim3(DI/256, MROWS), 256, 0, stream>>>(pj, dt_proj_w + (size_t)l*DI*RK,
                                                  dt_proj_b + (size_t)l*DI, dtb);
    k_scan<<<dim3(DI, BB), 256, 0, stream>>>(dtb, pj, xs,
                                             A_log + (size_t)l*DI*NS, y);
    k_gate<<<(MROWS*DI)/256, 256, 0, stream>>>(y, xs, xz, Dp + (size_t)l*DI);
    // h += y @ out_proj_w[l]^T : M=1024 N=768 K=1536 (64x64 tiles)
    k_gemm_nt<2,2,true><<<dim3(DM/64, MROWS/64), 256, 0, stream>>>(
        y, out_proj_w + (size_t)l*DM*DI, h, MROWS, DM, DI);
  }

  k_rmsnorm<<<MROWS, 256, 0, stream>>>(h, final_norm_w, r);
  // logits = r @ embed^T : M=1024 N=50280 K=768 (128x128 tiles)
  k_gemm_nt<4,4,false><<<dim3((50280 + 127)/128, MROWS/128), 256, 0, stream>>>(
      r, embed, out, MROWS, 50280, 768);
}